// Round 3
// baseline (221.780 us; speedup 1.0000x reference)
//
#include <hip/hip_runtime.h>
#include <hip/hip_bf16.h>

typedef __bf16 bf16x8 __attribute__((ext_vector_type(8)));
typedef __bf16 bf16x4 __attribute__((ext_vector_type(4)));
typedef float f32x4 __attribute__((ext_vector_type(4)));

#define KDIM 4096   // K = 128 blocks * 32
#define NDIM 4096   // N = 128 blocks * 32
#define NBJ  128    // output block-columns
#define KB   128    // input  block-rows

// ---- fused prep: [0, nbCvt) cvt+permute x | [nbCvt, +nnz) wtrans | last: csc
__global__ __launch_bounds__(256) void k_prep(
    const float* __restrict__ x, const float* __restrict__ w,
    const int* __restrict__ idx_i, const int* __restrict__ idx_j,
    __bf16* __restrict__ xb, __bf16* __restrict__ wT,
    int* __restrict__ colptr, int* __restrict__ colinfo,
    int nnz, int M, int nbCvt) {
    __shared__ char smem[2176];
    int b = blockIdx.x, t = threadIdx.x;

    if (b < nbCvt) {
        // xb[i][m][k] = bf16(x[m][i*32+k]); 64 rows per WG
        int i  = b & (KB - 1);
        int m0 = (b >> 7) * 64;
        int q  = t & 3, r = t >> 2;
        const float* xp = x + (size_t)(m0 + r) * KDIM + i * 32 + q * 8;
        float4 u = ((const float4*)xp)[0];
        float4 v = ((const float4*)xp)[1];
        bf16x8 o;
        o[0]=(__bf16)u.x; o[1]=(__bf16)u.y; o[2]=(__bf16)u.z; o[3]=(__bf16)u.w;
        o[4]=(__bf16)v.x; o[5]=(__bf16)v.y; o[6]=(__bf16)v.z; o[7]=(__bf16)v.w;
        *(bf16x8*)(xb + ((size_t)i * M + m0 + r) * 32 + q * 8) = o;
    } else if (b < nbCvt + nnz) {
        // wT[n][c][k] = bf16(w[n][k][c])
        auto tile = (__bf16(*)[33])smem;
        int n = b - nbCvt;
        float4 v = ((const float4*)(w + (size_t)n * 1024))[t];
        int e = t * 4, k = e >> 5, c = e & 31;
        tile[k][c + 0] = (__bf16)v.x; tile[k][c + 1] = (__bf16)v.y;
        tile[k][c + 2] = (__bf16)v.z; tile[k][c + 3] = (__bf16)v.w;
        __syncthreads();
        int f = t * 4, cc = f >> 5, kk = f & 31;
        bf16x4 o;
        o[0] = tile[kk + 0][cc]; o[1] = tile[kk + 1][cc];
        o[2] = tile[kk + 2][cc]; o[3] = tile[kk + 3][cc];
        ((bf16x4*)(wT + (size_t)n * 1024))[t] = o;
    } else {
        // CSC build: colptr + packed (ib<<16)|n colinfo
        int* cnt = (int*)smem;          // [NBJ]
        int* cur = cnt + NBJ;           // [NBJ]
        if (t < NBJ) cnt[t] = 0;
        __syncthreads();
        for (int n = t; n < nnz; n += 256) atomicAdd(&cnt[idx_j[n]], 1);
        __syncthreads();
        int mycount = (t < NBJ) ? cnt[t] : 0;
        for (int off = 1; off < NBJ; off <<= 1) {
            int add = (t < NBJ && t >= off) ? cnt[t - off] : 0;
            __syncthreads();
            if (t < NBJ) cnt[t] += add;
            __syncthreads();
        }
        if (t < NBJ) {
            colptr[t + 1] = cnt[t];
            cur[t] = cnt[t] - mycount;
            if (t == 0) colptr[0] = 0;
        }
        __syncthreads();
        for (int n = t; n < nnz; n += 256) {
            int j = idx_j[n];
            int pos = atomicAdd(&cur[j], 1);
            colinfo[pos] = (idx_i[n] << 16) | n;
        }
    }
}

// ---- main kernel ------------------------------------------------------------
// 16 output rows per wave: pipeline stage = {1 A-frag, 2 B-frags} = 12 VGPR,
// acc = 8.  Depth-4 rotation at ~70 total regs keeps ~7 waves/SIMD resident
// AND 4-iter lookahead — resolves the round-2 register/occupancy deadlock.
// rc-major XCD decode retained (FETCH 72->53 MB proven in round 2).
struct Frag { bf16x8 a, b0, b1; };

#define MFMA2(F)                                                               \
    acc0 = __builtin_amdgcn_mfma_f32_16x16x32_bf16(F.a, F.b0, acc0, 0, 0, 0);  \
    acc1 = __builtin_amdgcn_mfma_f32_16x16x32_bf16(F.a, F.b1, acc1, 0, 0, 0);

__global__ __launch_bounds__(256) void k_bsmm(
    const __bf16* __restrict__ xb, const __bf16* __restrict__ wT,
    const int* __restrict__ colptr, const int* __restrict__ colinfo,
    float* __restrict__ y, int M) {
    int RCH = M >> 6;                     // 64-row chunks (4 waves x 16 rows)
    int l = blockIdx.x;
    int rc, j;
    if ((RCH & 7) == 0) {
        // XCD s (= l%8 round-robin) walks all 128 j of one row-chunk, then next
        int rps = RCH >> 3;
        int s = l & 7, u = l >> 3;
        rc = s * rps + (u >> 7);
        j  = u & (NBJ - 1);
    } else {
        rc = l % RCH; j = l / RCH;
    }
    int lane = threadIdx.x & 63, wave = threadIdx.x >> 6;
    int quad = lane >> 4, l16 = lane & 15;
    int wrow = rc * 64 + wave * 16;

    int beg = colptr[j], end = colptr[j + 1];
    int cnt = end - beg;

    f32x4 acc0 = {}, acc1 = {};

    if (cnt > 0) {
        size_t strideA = (size_t)M * 32;                       // elems per ib slab
        const __bf16* xbase = xb + (size_t)(wrow + l16) * 32 + quad * 8;
        const __bf16* wbase = wT + l16 * 32 + quad * 8;
        int cap = cnt - 1;

        if (cnt <= 64) {
            int einfo = colinfo[beg + (lane <= cap ? lane : cap)];
            auto fetch = [&](int p) {
                int pp = p <= cap ? p : cap;
                int ee = __shfl(einfo, pp);
                int n = ee & 0xFFFF, ib = ee >> 16;
                Frag f;
                f.a  = *(const bf16x8*)(xbase + (size_t)ib * strideA);
                const __bf16* wp = wbase + (size_t)n * 1024;
                f.b0 = *(const bf16x8*)(wp);
                f.b1 = *(const bf16x8*)(wp + 512);
                return f;
            };
            Frag f0 = fetch(0);
            Frag f1 = fetch(1);
            Frag f2 = fetch(2);
            Frag f3 = fetch(3);
            int p = 0;
            for (; p + 4 <= cnt; p += 4) {
                MFMA2(f0); f0 = fetch(p + 4);
                MFMA2(f1); f1 = fetch(p + 5);
                MFMA2(f2); f2 = fetch(p + 6);
                MFMA2(f3); f3 = fetch(p + 7);
            }
            if (p < cnt)     { MFMA2(f0); }
            if (p + 1 < cnt) { MFMA2(f1); }
            if (p + 2 < cnt) { MFMA2(f2); }
            if (p + 3 < cnt) { MFMA2(f3); }
        } else {
            auto fetch = [&](int p) {
                int pp = p <= cap ? p : cap;
                int ee = colinfo[beg + pp];
                int n = ee & 0xFFFF, ib = ee >> 16;
                Frag f;
                f.a  = *(const bf16x8*)(xbase + (size_t)ib * strideA);
                const __bf16* wp = wbase + (size_t)n * 1024;
                f.b0 = *(const bf16x8*)(wp);
                f.b1 = *(const bf16x8*)(wp + 512);
                return f;
            };
            Frag f0 = fetch(0);
            Frag f1 = fetch(1);
            Frag f2 = fetch(2);
            Frag f3 = fetch(3);
            int p = 0;
            for (; p + 4 <= cnt; p += 4) {
                MFMA2(f0); f0 = fetch(p + 4);
                MFMA2(f1); f1 = fetch(p + 5);
                MFMA2(f2); f2 = fetch(p + 6);
                MFMA2(f3); f3 = fetch(p + 7);
            }
            if (p < cnt)     { MFMA2(f0); }
            if (p + 1 < cnt) { MFMA2(f1); }
            if (p + 2 < cnt) { MFMA2(f2); }
            if (p + 3 < cnt) { MFMA2(f3); }
        }
    }

    // C/D layout: row = quad*4 + reg, col = lane&15
    #pragma unroll
    for (int reg = 0; reg < 4; ++reg) {
        int row = wrow + quad * 4 + reg;
        y[(size_t)row * NDIM + j * 32 + l16]      = acc0[reg];
        y[(size_t)row * NDIM + j * 32 + 16 + l16] = acc1[reg];
    }
}

// ---- fallback (no workspace): fp32 reads, convert in-kernel -----------------
__global__ __launch_bounds__(256) void k_bsmm_nows(
    const float* __restrict__ x, const float* __restrict__ w,
    const int* __restrict__ idx_i, const int* __restrict__ idx_j,
    float* __restrict__ y, int nnz) {
    __shared__ int list[256];
    __shared__ int listn;
    __shared__ __bf16 tw[32][40];
    int j = blockIdx.y;
    int tid = threadIdx.x;
    int lane = tid & 63, wave = tid >> 6;
    int quad = lane >> 4, l16 = lane & 15;
    int wrow = blockIdx.x * 256 + wave * 64;

    if (tid == 0) listn = 0;
    __syncthreads();
    for (int n = tid; n < nnz; n += 256)
        if (idx_j[n] == j) { int p = atomicAdd(&listn, 1); list[p & 255] = n; }
    __syncthreads();
    int cnt = listn;

    f32x4 acc[4][2] = {};
    for (int p = 0; p < cnt; ++p) {
        int n = list[p];
        int ib = idx_i[n];
        {
            float4 v = ((const float4*)(w + (size_t)n * 1024))[tid];
            int e = tid * 4, k = e >> 5, c = e & 31;
            tw[c + 0][k] = (__bf16)v.x; tw[c + 1][k] = (__bf16)v.y;
            tw[c + 2][k] = (__bf16)v.z; tw[c + 3][k] = (__bf16)v.w;
        }
        __syncthreads();
        bf16x8 a[4];
        #pragma unroll
        for (int r = 0; r < 4; ++r) {
            const float* xp = x + (size_t)(wrow + r * 16 + l16) * KDIM + ib * 32 + quad * 8;
            float4 u = *(const float4*)(xp);
            float4 v = *(const float4*)(xp + 4);
            a[r][0] = (__bf16)u.x; a[r][1] = (__bf16)u.y; a[r][2] = (__bf16)u.z; a[r][3] = (__bf16)u.w;
            a[r][4] = (__bf16)v.x; a[r][5] = (__bf16)v.y; a[r][6] = (__bf16)v.z; a[r][7] = (__bf16)v.w;
        }
        bf16x8 b0 = *(const bf16x8*)&tw[l16][quad * 8];
        bf16x8 b1 = *(const bf16x8*)&tw[l16 + 16][quad * 8];
        #pragma unroll
        for (int r = 0; r < 4; ++r) {
            acc[r][0] = __builtin_amdgcn_mfma_f32_16x16x32_bf16(a[r], b0, acc[r][0], 0, 0, 0);
            acc[r][1] = __builtin_amdgcn_mfma_f32_16x16x32_bf16(a[r], b1, acc[r][1], 0, 0, 0);
        }
        __syncthreads();
    }

    #pragma unroll
    for (int r = 0; r < 4; ++r)
        #pragma unroll
        for (int ch = 0; ch < 2; ++ch)
            #pragma unroll
            for (int reg = 0; reg < 4; ++reg) {
                int row = wrow + r * 16 + quad * 4 + reg;
                int col = j * 32 + ch * 16 + l16;
                y[(size_t)row * NDIM + col] = acc[r][ch][reg];
            }
}

extern "C" void kernel_launch(void* const* d_in, const int* in_sizes, int n_in,
                              void* d_out, int out_size, void* d_ws, size_t ws_size,
                              hipStream_t stream) {
    const float* x     = (const float*)d_in[0];
    const float* w     = (const float*)d_in[1];
    const int*   idx_i = (const int*)d_in[2];
    const int*   idx_j = (const int*)d_in[3];
    float*       y     = (float*)d_out;

    int nnz = in_sizes[2];
    int M   = in_sizes[0] / KDIM;                   // 4096

    size_t xb_bytes = (size_t)M * KDIM * 2;         // 32 MB
    size_t wt_bytes = (size_t)nnz * 1024 * 2;
    size_t need = xb_bytes + wt_bytes + (size_t)(NBJ + 2 + nnz) * 4;

    if (ws_size >= need && (M & 255) == 0) {
        __bf16* xb      = (__bf16*)d_ws;
        __bf16* wT      = (__bf16*)((char*)d_ws + xb_bytes);
        int*    colptr  = (int*)((char*)d_ws + xb_bytes + wt_bytes);
        int*    colinfo = colptr + NBJ + 1;
        int nbCvt = KB * (M / 64);                  // 8192
        k_prep<<<nbCvt + nnz + 1, 256, 0, stream>>>(x, w, idx_i, idx_j,
                                                    xb, wT, colptr, colinfo,
                                                    nnz, M, nbCvt);
        k_bsmm<<<(M / 64) * NBJ, 256, 0, stream>>>(xb, wT, colptr, colinfo, y, M);
    } else {
        k_bsmm_nows<<<dim3(M / 256, NBJ), 256, 0, stream>>>(x, w, idx_i, idx_j, y, nnz);
    }
}

// Round 4
// 166.815 us; speedup vs baseline: 1.3295x; 1.3295x over previous
//
#include <hip/hip_runtime.h>
#include <hip/hip_bf16.h>

typedef __bf16 bf16x8 __attribute__((ext_vector_type(8)));
typedef __bf16 bf16x4 __attribute__((ext_vector_type(4)));
typedef float f32x4 __attribute__((ext_vector_type(4)));

#define KDIM 4096   // K = 128 blocks * 32
#define NDIM 4096   // N = 128 blocks * 32
#define NBJ  128    // output block-columns
#define KB   128    // input  block-rows

#define NB      14      // wT blocks staged in LDS per batch
#define BLK_LDS 2560    // 32 rows * 80 B (64 B data + 16 B pad) per block

// ---- fused prep: [0, nbCvt) cvt+permute x | [nbCvt, +nnz) wtrans | last: csc
__global__ __launch_bounds__(256) void k_prep(
    const float* __restrict__ x, const float* __restrict__ w,
    const int* __restrict__ idx_i, const int* __restrict__ idx_j,
    __bf16* __restrict__ xb, __bf16* __restrict__ wT,
    int* __restrict__ colptr, int* __restrict__ colinfo,
    int nnz, int M, int nbCvt) {
    __shared__ char smem[2176];
    int b = blockIdx.x, t = threadIdx.x;

    if (b < nbCvt) {
        // xb[i][m][k] = bf16(x[m][i*32+k]); 64 rows per WG
        int i  = b & (KB - 1);
        int m0 = (b >> 7) * 64;
        int q  = t & 3, r = t >> 2;
        const float* xp = x + (size_t)(m0 + r) * KDIM + i * 32 + q * 8;
        float4 u = ((const float4*)xp)[0];
        float4 v = ((const float4*)xp)[1];
        bf16x8 o;
        o[0]=(__bf16)u.x; o[1]=(__bf16)u.y; o[2]=(__bf16)u.z; o[3]=(__bf16)u.w;
        o[4]=(__bf16)v.x; o[5]=(__bf16)v.y; o[6]=(__bf16)v.z; o[7]=(__bf16)v.w;
        *(bf16x8*)(xb + ((size_t)i * M + m0 + r) * 32 + q * 8) = o;
    } else if (b < nbCvt + nnz) {
        // wT[n][c][k] = bf16(w[n][k][c])
        auto tile = (__bf16(*)[33])smem;
        int n = b - nbCvt;
        float4 v = ((const float4*)(w + (size_t)n * 1024))[t];
        int e = t * 4, k = e >> 5, c = e & 31;
        tile[k][c + 0] = (__bf16)v.x; tile[k][c + 1] = (__bf16)v.y;
        tile[k][c + 2] = (__bf16)v.z; tile[k][c + 3] = (__bf16)v.w;
        __syncthreads();
        int f = t * 4, cc = f >> 5, kk = f & 31;
        bf16x4 o;
        o[0] = tile[kk + 0][cc]; o[1] = tile[kk + 1][cc];
        o[2] = tile[kk + 2][cc]; o[3] = tile[kk + 3][cc];
        ((bf16x4*)(wT + (size_t)n * 1024))[t] = o;
    } else {
        // CSC build: colptr + packed (ib<<16)|n colinfo
        int* cnt = (int*)smem;          // [NBJ]
        int* cur = cnt + NBJ;           // [NBJ]
        if (t < NBJ) cnt[t] = 0;
        __syncthreads();
        for (int n = t; n < nnz; n += 256) atomicAdd(&cnt[idx_j[n]], 1);
        __syncthreads();
        int mycount = (t < NBJ) ? cnt[t] : 0;
        for (int off = 1; off < NBJ; off <<= 1) {
            int add = (t < NBJ && t >= off) ? cnt[t - off] : 0;
            __syncthreads();
            if (t < NBJ) cnt[t] += add;
            __syncthreads();
        }
        if (t < NBJ) {
            colptr[t + 1] = cnt[t];
            cur[t] = cnt[t] - mycount;
            if (t == 0) colptr[0] = 0;
        }
        __syncthreads();
        for (int n = t; n < nnz; n += 256) {
            int j = idx_j[n];
            int pos = atomicAdd(&cur[j], 1);
            colinfo[pos] = (idx_i[n] << 16) | n;
        }
    }
}

// ---- main kernel ------------------------------------------------------------
// 64 rows/wave (round-0 shape, proven best), rc-major XCD decode (round-2,
// proven -26% fetch), and wT staged in LDS so the register pipeline holds
// A-frags only: 3-deep A rotation (48 VGPR) + 32 acc fits under the 128-reg
// cap that __launch_bounds__(256,4) imposes -> 4 WGs/CU resident.
// LDS B rows padded 64B->80B: 2-way bank aliasing only (free per m136).
struct AFrag { bf16x8 a0, a1, a2, a3; };

#define MFMA8(A, B0, B1)                                                       \
    acc[0][0] = __builtin_amdgcn_mfma_f32_16x16x32_bf16(A.a0, B0, acc[0][0], 0, 0, 0); \
    acc[0][1] = __builtin_amdgcn_mfma_f32_16x16x32_bf16(A.a0, B1, acc[0][1], 0, 0, 0); \
    acc[1][0] = __builtin_amdgcn_mfma_f32_16x16x32_bf16(A.a1, B0, acc[1][0], 0, 0, 0); \
    acc[1][1] = __builtin_amdgcn_mfma_f32_16x16x32_bf16(A.a1, B1, acc[1][1], 0, 0, 0); \
    acc[2][0] = __builtin_amdgcn_mfma_f32_16x16x32_bf16(A.a2, B0, acc[2][0], 0, 0, 0); \
    acc[2][1] = __builtin_amdgcn_mfma_f32_16x16x32_bf16(A.a2, B1, acc[2][1], 0, 0, 0); \
    acc[3][0] = __builtin_amdgcn_mfma_f32_16x16x32_bf16(A.a3, B0, acc[3][0], 0, 0, 0); \
    acc[3][1] = __builtin_amdgcn_mfma_f32_16x16x32_bf16(A.a3, B1, acc[3][1], 0, 0, 0);

__global__ __launch_bounds__(256, 4) void k_bsmm(
    const __bf16* __restrict__ xb, const __bf16* __restrict__ wT,
    const int* __restrict__ colptr, const int* __restrict__ colinfo,
    float* __restrict__ y, int M) {
    __shared__ int nfo[NB];
    __shared__ __attribute__((aligned(16))) char wbuf[NB * BLK_LDS];  // 35 KB

    int RCH = M >> 8;
    int l = blockIdx.x;
    int rc, j;
    if ((RCH & 7) == 0) {
        // XCD s (= l%8 round-robin) walks all 128 j of one 256-row chunk,
        // then the next chunk: per-XCD xb working set = 2 MB (L2-resident).
        int rps = RCH >> 3;
        int s = l & 7, u = l >> 3;
        rc = s * rps + (u >> 7);
        j  = u & (NBJ - 1);
    } else {
        rc = l % RCH; j = l / RCH;
    }
    int t = threadIdx.x;
    int lane = t & 63, wave = t >> 6;
    int quad = lane >> 4, l16 = lane & 15;
    int wrow = rc * 256 + wave * 64;

    int beg = colptr[j], end = colptr[j + 1];

    f32x4 acc[4][2] = {};

    size_t strideA = (size_t)M * 32;                           // elems per ib slab
    const __bf16* xbase = xb + (size_t)(wrow + l16) * 32 + quad * 8;
    const char*   wread = wbuf + l16 * 80 + quad * 16;

    for (int bb = beg; bb < end; bb += NB) {
        int cb = end - bb; if (cb > NB) cb = NB;
        if (bb > beg) __syncthreads();                         // wbuf reuse guard
        if (t < cb) nfo[t] = colinfo[bb + t];
        __syncthreads();

        // stage cb wT blocks into LDS (coalesced 16B reads, padded writes)
        for (int c = t; c < cb * 128; c += 256) {
            int b = c >> 7, w16 = c & 127;
            int n = nfo[b] & 0xFFFF;
            bf16x8 v = *(const bf16x8*)(wT + (size_t)n * 1024 + w16 * 8);
            *(bf16x8*)(wbuf + b * BLK_LDS + (w16 >> 2) * 80 + (w16 & 3) * 16) = v;
        }
        __syncthreads();

        auto fa = [&](int p) {
            int pp = p < cb ? p : cb - 1;
            int ib = nfo[pp] >> 16;                            // uniform LDS read
            AFrag f;
            const __bf16* xp = xbase + (size_t)ib * strideA;
            f.a0 = *(const bf16x8*)(xp);
            f.a1 = *(const bf16x8*)(xp + 16 * 32);
            f.a2 = *(const bf16x8*)(xp + 32 * 32);
            f.a3 = *(const bf16x8*)(xp + 48 * 32);
            return f;
        };
        AFrag A0 = fa(0);
        AFrag A1 = fa(1);
        AFrag A2 = fa(2);
        for (int p = 0; p < cb; ++p) {
            const char* wp = wread + p * BLK_LDS;
            bf16x8 b0 = *(const bf16x8*)(wp);
            bf16x8 b1 = *(const bf16x8*)(wp + 16 * 80);
            MFMA8(A0, b0, b1);
            A0 = A1; A1 = A2; A2 = fa(p + 3);
        }
    }

    // C/D layout: row = quad*4 + reg, col = lane&15
    #pragma unroll
    for (int r = 0; r < 4; ++r)
        #pragma unroll
        for (int ch = 0; ch < 2; ++ch)
            #pragma unroll
            for (int reg = 0; reg < 4; ++reg) {
                int row = wrow + r * 16 + quad * 4 + reg;
                int col = j * 32 + ch * 16 + l16;
                y[(size_t)row * NDIM + col] = acc[r][ch][reg];
            }
}

// ---- fallback (no workspace): fp32 reads, convert in-kernel -----------------
__global__ __launch_bounds__(256) void k_bsmm_nows(
    const float* __restrict__ x, const float* __restrict__ w,
    const int* __restrict__ idx_i, const int* __restrict__ idx_j,
    float* __restrict__ y, int nnz) {
    __shared__ int list[256];
    __shared__ int listn;
    __shared__ __bf16 tw[32][40];
    int j = blockIdx.y;
    int tid = threadIdx.x;
    int lane = tid & 63, wave = tid >> 6;
    int quad = lane >> 4, l16 = lane & 15;
    int wrow = blockIdx.x * 256 + wave * 64;

    if (tid == 0) listn = 0;
    __syncthreads();
    for (int n = tid; n < nnz; n += 256)
        if (idx_j[n] == j) { int p = atomicAdd(&listn, 1); list[p & 255] = n; }
    __syncthreads();
    int cnt = listn;

    f32x4 acc[4][2] = {};
    for (int p = 0; p < cnt; ++p) {
        int n = list[p];
        int ib = idx_i[n];
        {
            float4 v = ((const float4*)(w + (size_t)n * 1024))[tid];
            int e = tid * 4, k = e >> 5, c = e & 31;
            tw[c + 0][k] = (__bf16)v.x; tw[c + 1][k] = (__bf16)v.y;
            tw[c + 2][k] = (__bf16)v.z; tw[c + 3][k] = (__bf16)v.w;
        }
        __syncthreads();
        bf16x8 a[4];
        #pragma unroll
        for (int r = 0; r < 4; ++r) {
            const float* xp = x + (size_t)(wrow + r * 16 + l16) * KDIM + ib * 32 + quad * 8;
            float4 u = *(const float4*)(xp);
            float4 v = *(const float4*)(xp + 4);
            a[r][0] = (__bf16)u.x; a[r][1] = (__bf16)u.y; a[r][2] = (__bf16)u.z; a[r][3] = (__bf16)u.w;
            a[r][4] = (__bf16)v.x; a[r][5] = (__bf16)v.y; a[r][6] = (__bf16)v.z; a[r][7] = (__bf16)v.w;
        }
        bf16x8 b0 = *(const bf16x8*)&tw[l16][quad * 8];
        bf16x8 b1 = *(const bf16x8*)&tw[l16 + 16][quad * 8];
        #pragma unroll
        for (int r = 0; r < 4; ++r) {
            acc[r][0] = __builtin_amdgcn_mfma_f32_16x16x32_bf16(a[r], b0, acc[r][0], 0, 0, 0);
            acc[r][1] = __builtin_amdgcn_mfma_f32_16x16x32_bf16(a[r], b1, acc[r][1], 0, 0, 0);
        }
        __syncthreads();
    }

    #pragma unroll
    for (int r = 0; r < 4; ++r)
        #pragma unroll
        for (int ch = 0; ch < 2; ++ch)
            #pragma unroll
            for (int reg = 0; reg < 4; ++reg) {
                int row = wrow + r * 16 + quad * 4 + reg;
                int col = j * 32 + ch * 16 + l16;
                y[(size_t)row * NDIM + col] = acc[r][ch][reg];
            }
}

extern "C" void kernel_launch(void* const* d_in, const int* in_sizes, int n_in,
                              void* d_out, int out_size, void* d_ws, size_t ws_size,
                              hipStream_t stream) {
    const float* x     = (const float*)d_in[0];
    const float* w     = (const float*)d_in[1];
    const int*   idx_i = (const int*)d_in[2];
    const int*   idx_j = (const int*)d_in[3];
    float*       y     = (float*)d_out;

    int nnz = in_sizes[2];
    int M   = in_sizes[0] / KDIM;                   // 4096

    size_t xb_bytes = (size_t)M * KDIM * 2;         // 32 MB
    size_t wt_bytes = (size_t)nnz * 1024 * 2;
    size_t need = xb_bytes + wt_bytes + (size_t)(NBJ + 2 + nnz) * 4;

    if (ws_size >= need && (M & 255) == 0 && nnz < 65536) {
        __bf16* xb      = (__bf16*)d_ws;
        __bf16* wT      = (__bf16*)((char*)d_ws + xb_bytes);
        int*    colptr  = (int*)((char*)d_ws + xb_bytes + wt_bytes);
        int*    colinfo = colptr + NBJ + 1;
        int nbCvt = KB * (M / 64);                  // 8192
        k_prep<<<nbCvt + nnz + 1, 256, 0, stream>>>(x, w, idx_i, idx_j,
                                                    xb, wT, colptr, colinfo,
                                                    nnz, M, nbCvt);
        k_bsmm<<<(M / 256) * NBJ, 256, 0, stream>>>(xb, wT, colptr, colinfo, y, M);
    } else {
        k_bsmm_nows<<<dim3(M / 256, NBJ), 256, 0, stream>>>(x, w, idx_i, idx_j, y, nnz);
    }
}